// Round 9
// baseline (591.229 us; speedup 1.0000x reference)
//
#include <hip/hip_runtime.h>
#include <cmath>
#include <cstdint>

// Problem constants (from reference)
constexpr int B_ = 8, N_ = 1024, M_ = 512, D_ = 128, S_ = 1536, L_ = 6, DFF_ = 512;
constexpr int ROWS = B_ * S_;    // 12288
constexpr int MAXDEG = 64;       // max attention row degree (actual ~4-20)
constexpr int LKEY = 32;         // LDS-cached keys per row (deg>32 ~ never)
constexpr int RPB  = 48;         // rows per block
constexpr int NBLK = ROWS / RPB; // 256 persistent blocks = 256 CUs (all resident)

typedef __bf16 bf16x8 __attribute__((ext_vector_type(8)));
typedef float  f32x4  __attribute__((ext_vector_type(4)));
typedef unsigned short u16x8 __attribute__((ext_vector_type(8)));

__device__ inline unsigned short f2bf(float f) {  // RNE fp32 -> bf16
  unsigned u = __float_as_uint(f);
  u += 0x7fffu + ((u >> 16) & 1u);
  return (unsigned short)(u >> 16);
}
__device__ inline float bf2f(unsigned short u) {
  return __uint_as_float(((unsigned)u) << 16);
}

// ---------------------------------------------------------------------------
// Adjacency from pcm (one wave per row). exp(-1e9-max) underflows to 0 in
// fp32 => sparse attention over this list == dense masked softmax.
// ---------------------------------------------------------------------------
__global__ void adj_kernel(const int* __restrict__ pcm, int* __restrict__ adj,
                           int* __restrict__ adjcnt) {
  int s = blockIdx.x;
  int lane = threadIdx.x;
  int count = 0;
  for (int base = 0; base < S_; base += 64) {
    int k = base + lane;
    bool allowed;
    if (k == s) allowed = true;
    else if (s < N_ && k >= N_) allowed = pcm[(k - N_) * N_ + s] != 0;
    else if (s >= N_ && k < N_) allowed = pcm[(s - N_) * N_ + k] != 0;
    else allowed = false;
    unsigned long long bal = __ballot(allowed);
    if (allowed) {
      int slot = count + __popcll(bal & ((1ull << lane) - 1ull));
      if (slot < MAXDEG) adj[s * MAXDEG + slot] = k;
    }
    count += __popcll(bal);
  }
  if (lane == 0) adjcnt[s] = count < MAXDEG ? count : MAXDEG;
}

// ---------------------------------------------------------------------------
// x init; also zeroes the grid-barrier counter (ws poisoned 0xAA per call).
// ---------------------------------------------------------------------------
__global__ void xinit_kernel(const float* __restrict__ r_t, const int* __restrict__ adj,
                             const int* __restrict__ adjcnt, const float* __restrict__ se,
                             const int* __restrict__ tt, const float* __restrict__ table,
                             float* __restrict__ x, unsigned* __restrict__ barrier_cnt) {
  int bs = blockIdx.x;
  int b = bs / S_, s = bs % S_;
  int d = threadIdx.x;
  if (bs == 0 && d == 0) *barrier_cnt = 0u;
  float node;
  if (s < N_) {
    node = fabsf(r_t[b * N_ + s]);
  } else {
    int cnt = adjcnt[s];
    float sum = 0.f;
    for (int j = 0; j < cnt; ++j) {
      int k = adj[s * MAXDEG + j];
      if (k < N_) {
        float r = r_t[b * N_ + k];
        sum += (r < 0.f) ? 1.f : (r > 0.f ? 0.f : 0.5f);
      }
    }
    node = fmodf(sum, 2.0f);
  }
  x[(size_t)bs * D_ + d] = table[tt[b] * D_ + d] * se[s * D_ + d] * node;
}

// ---------------------------------------------------------------------------
// Weight convert: fp32 [K][N] -> bf16 transposed [N][K], per layer packed as
//   [3*128][128] (q,k,v) | [128][128] (o) | [512][128] (w1) | [128][512] (w2)
// ---------------------------------------------------------------------------
constexpr int WSEG_QKV = 3 * D_ * D_;
constexpr int WSEG_O   = D_ * D_;
constexpr int WSEG_1   = D_ * DFF_;
constexpr int WSEG_2   = DFF_ * D_;
constexpr int WLAYER   = WSEG_QKV + WSEG_O + WSEG_1 + WSEG_2;  // 196608

__global__ void wconv_kernel(const float* __restrict__ Wq, const float* __restrict__ Wk,
                             const float* __restrict__ Wv, const float* __restrict__ Wo,
                             const float* __restrict__ W1, const float* __restrict__ W2,
                             unsigned short* __restrict__ out) {
  int idx = blockIdx.x * blockDim.x + threadIdx.x;
  if (idx >= L_ * WLAYER) return;
  int l = idx / WLAYER, r = idx % WLAYER;
  float v;
  if (r < WSEG_QKV) {
    int which = r / (D_ * D_), i = r % (D_ * D_);
    int n = i / D_, kk = i % D_;
    const float* W = which == 0 ? Wq : (which == 1 ? Wk : Wv);
    v = W[(size_t)l * D_ * D_ + kk * D_ + n];
  } else if (r < WSEG_QKV + WSEG_O) {
    int i = r - WSEG_QKV;
    int n = i / D_, kk = i % D_;
    v = Wo[(size_t)l * D_ * D_ + kk * D_ + n];
  } else if (r < WSEG_QKV + WSEG_O + WSEG_1) {
    int i = r - WSEG_QKV - WSEG_O;
    int n = i / D_, kk = i % D_;
    v = W1[(size_t)l * D_ * DFF_ + kk * DFF_ + n];
  } else {
    int i = r - WSEG_QKV - WSEG_O - WSEG_1;
    int n = i / DFF_, kk = i % DFF_;
    v = W2[(size_t)l * DFF_ * D_ + kk * D_ + n];
  }
  out[idx] = f2bf(v);
}

// ---------------------------------------------------------------------------
// MFMA helper: wave tile = 16 rows x 64 cols (4 tiles of 16x16), K=128 in 4
// steps of 32. LDS: 16B chunks XOR-swizzled [row*128 + ((c^(row&15))<<3)].
// ---------------------------------------------------------------------------
__device__ __forceinline__ void mfma4(const unsigned short* As, const unsigned short* Bs,
                                      int rowbase, int colbase, int quad, int l16,
                                      f32x4 (&acc)[4]) {
#pragma unroll
  for (int kk = 0; kk < 4; ++kk) {
    int cb = kk * 4 + quad;
    int row = rowbase + l16;
    bf16x8 a = __builtin_bit_cast(bf16x8, *(const uint4*)&As[row * 128 + ((cb ^ (row & 15)) << 3)]);
    bf16x8 bb[4];
#pragma unroll
    for (int ct = 0; ct < 4; ++ct) {
      int n = colbase + ct * 16 + l16;
      bb[ct] = __builtin_bit_cast(bf16x8, *(const uint4*)&Bs[n * 128 + ((cb ^ (n & 15)) << 3)]);
    }
#pragma unroll
    for (int ct = 0; ct < 4; ++ct)
      acc[ct] = __builtin_amdgcn_mfma_f32_16x16x32_bf16(a, bb[ct], acc[ct], 0, 0, 0);
  }
}

// ---- register-prefetch staging: 2048 uint4 per 128x128 bf16 tile ----------
// issue: start global loads into regs (one stage ahead). commit: regs -> Bs.
__device__ __forceinline__ void issue_stage(const unsigned short* base, int strideHalf,
                                            uint4 (&r)[6], int t) {
#pragma unroll
  for (int k = 0; k < 6; ++k) {
    int idx = t + k * 384;
    if (idx < 2048) {
      int rr = idx >> 4, cc = idx & 15;
      r[k] = *(const uint4*)&base[(size_t)rr * strideHalf + cc * 8];
    }
  }
}
__device__ __forceinline__ void commit_stage(uint4 (&r)[6], unsigned short* Bs, int t) {
#pragma unroll
  for (int k = 0; k < 6; ++k) {
    int idx = t + k * 384;
    if (idx < 2048) {
      int rr = idx >> 4, cc = idx & 15;
      *(uint4*)&Bs[rr * 128 + ((cc ^ (rr & 15)) << 3)] = r[k];
    }
  }
}

// ---------------------------------------------------------------------------
// Grid barrier (R6/R8-proven): fence release + device atomic + spin + fence.
// ---------------------------------------------------------------------------
__device__ __forceinline__ void grid_barrier(unsigned* cnt, unsigned target) {
  __syncthreads();
  if (threadIdx.x == 0) {
    __threadfence();
    __hip_atomic_fetch_add(cnt, 1u, __ATOMIC_RELEASE, __HIP_MEMORY_SCOPE_AGENT);
    while (__hip_atomic_load(cnt, __ATOMIC_ACQUIRE, __HIP_MEMORY_SCOPE_AGENT) < target) {
      __builtin_amdgcn_s_sleep(8);
    }
    __threadfence();
  }
  __syncthreads();
}

// ---------------------------------------------------------------------------
// Persistent mega-kernel, software-pipelined weight staging.
// grid = 256 blocks x 384 thr (6 waves); block owns 48 rows.
// x in registers; Q block-local (Cs); only bf16 K/V cross blocks (dbuffered);
// one fenced barrier per layer. Weight tiles prefetched one stage ahead into
// registers so staging latency hides under MFMA/LN/attention work.
// LDS: As 12K + Bs 32K + Cs 12K + adj cache ~6.3K + red ~0.8K ~= 63 KB.
// ---------------------------------------------------------------------------
__global__ void __launch_bounds__(384) mega_kernel(
    const float* __restrict__ x0, unsigned short* __restrict__ kv0,
    unsigned short* __restrict__ kv1, const unsigned short* __restrict__ wbf,
    const float* __restrict__ g1, const float* __restrict__ b1,
    const float* __restrict__ g2, const float* __restrict__ b2,
    const int* __restrict__ tt, const float* __restrict__ table,
    const int* __restrict__ adj, const int* __restrict__ adjc,
    const float* __restrict__ fcw, const float* __restrict__ fcb,
    float* __restrict__ out, unsigned* barrier_cnt) {
  __shared__ unsigned short As[RPB * 128];
  __shared__ unsigned short Bs[128 * 128];
  __shared__ unsigned short Cs[RPB * 128];
  __shared__ float red1[2][RPB], red2[2][RPB];
  __shared__ int sKeys[RPB * LKEY];
  __shared__ int sCnt[RPB];
  const int row0 = blockIdx.x * RPB;
  const int b = row0 / S_;
  const int bS = b * S_;
  const int t = threadIdx.x, w = t >> 6, lane = t & 63, quad = lane >> 4, l16 = lane & 15;
  const int wr = w >> 1, wc = w & 1;
  const int rowbase = wr * 16, colbase = wc * 64;
  const int tbase = tt[b] * D_;

  // persistent x in registers (MFMA C-layout)
  f32x4 xreg[4];
#pragma unroll
  for (int ct = 0; ct < 4; ++ct)
#pragma unroll
    for (int i = 0; i < 4; ++i) {
      int row = row0 + rowbase + quad * 4 + i;
      int col = colbase + ct * 16 + l16;
      xreg[ct][i] = x0[(size_t)row * D_ + col];
    }
  // cache block's adjacency in LDS (fences would otherwise evict it each layer)
  if (t < RPB) sCnt[t] = adjc[row0 + t - bS];
  for (int i = t; i < RPB * LKEY; i += 384) {
    int r = i / LKEY, j = i % LKEY;
    sKeys[i] = adj[(row0 + r - bS) * MAXDEG + j];  // tail values unused (clamped)
  }
  // prime the pipeline: Wq of layer 0
  uint4 pre[6];
  issue_stage(wbf, 128, pre, t);

  for (int l = 0; l < L_; ++l) {
    const unsigned short* wl = wbf + (size_t)l * WLAYER;
    const float* g1l = g1 + l * D_;
    const float* b1l = b1 + l * D_;
    const float* g2l = g2 + l * D_;
    const float* b2l = b2 + l * D_;
    unsigned short* kv = (l & 1) ? kv1 : kv0;

    // ---------------- LN1 on register x -> bf16 h in As --------------------
    float mu1[4], rs1[4];
#pragma unroll
    for (int i = 0; i < 4; ++i) {
      float s = xreg[0][i] + xreg[1][i] + xreg[2][i] + xreg[3][i];
      for (int off = 1; off < 16; off <<= 1) s += __shfl_xor(s, off);
      if (l16 == 0) red1[wc][rowbase + quad * 4 + i] = s;
    }
    __syncthreads();
#pragma unroll
    for (int i = 0; i < 4; ++i) {
      int r = rowbase + quad * 4 + i;
      mu1[i] = (red1[0][r] + red1[1][r]) * (1.f / 128.f);
      float sq = 0.f;
#pragma unroll
      for (int ct = 0; ct < 4; ++ct) { float d = xreg[ct][i] - mu1[i]; sq += d * d; }
      for (int off = 1; off < 16; off <<= 1) sq += __shfl_xor(sq, off);
      if (l16 == 0) red2[wc][r] = sq;
    }
    __syncthreads();
#pragma unroll
    for (int i = 0; i < 4; ++i) {
      int r = rowbase + quad * 4 + i;
      rs1[i] = rsqrtf((red2[0][r] + red2[1][r]) * (1.f / 128.f) + 1e-5f);
    }
#pragma unroll
    for (int ct = 0; ct < 4; ++ct)
#pragma unroll
      for (int i = 0; i < 4; ++i) {
        int rowL = rowbase + quad * 4 + i;
        int col = colbase + ct * 16 + l16;
        float h = (xreg[ct][i] - mu1[i]) * rs1[i] * g1l[col] + b1l[col];
        As[rowL * 128 + (((col >> 3) ^ (rowL & 15)) << 3) + (col & 7)] = f2bf(h);
      }
    __syncthreads();                       // As(h) ready; Bs free
    // ---------------- QKV: q->Cs, k/v->global kv (pipelined) ---------------
    commit_stage(pre, Bs, t);              // Wq
    __syncthreads();
    issue_stage(wl + (size_t)128 * 128, 128, pre, t);   // -> Wk
    {
      f32x4 acc[4];
#pragma unroll
      for (int j = 0; j < 4; ++j) acc[j] = f32x4{0.f, 0.f, 0.f, 0.f};
      mfma4(As, Bs, rowbase, colbase, quad, l16, acc);
#pragma unroll
      for (int ct = 0; ct < 4; ++ct)
#pragma unroll
        for (int i = 0; i < 4; ++i) {
          int rowL = rowbase + quad * 4 + i;
          int col = colbase + ct * 16 + l16;
          Cs[rowL * 128 + (((col >> 3) ^ (rowL & 15)) << 3) + (col & 7)] = f2bf(acc[ct][i]);
        }
    }
    __syncthreads();
    commit_stage(pre, Bs, t);              // Wk
    __syncthreads();
    issue_stage(wl + (size_t)256 * 128, 128, pre, t);   // -> Wv
    {
      f32x4 acc[4];
#pragma unroll
      for (int j = 0; j < 4; ++j) acc[j] = f32x4{0.f, 0.f, 0.f, 0.f};
      mfma4(As, Bs, rowbase, colbase, quad, l16, acc);
#pragma unroll
      for (int ct = 0; ct < 4; ++ct)
#pragma unroll
        for (int i = 0; i < 4; ++i) {
          int row = row0 + rowbase + quad * 4 + i;
          int col = colbase + ct * 16 + l16;
          kv[(size_t)row * 256 + col] = f2bf(acc[ct][i]);
        }
    }
    __syncthreads();
    commit_stage(pre, Bs, t);              // Wv
    __syncthreads();
    issue_stage(wl + WSEG_QKV, 128, pre, t);            // -> Wo
    {
      f32x4 acc[4];
#pragma unroll
      for (int j = 0; j < 4; ++j) acc[j] = f32x4{0.f, 0.f, 0.f, 0.f};
      mfma4(As, Bs, rowbase, colbase, quad, l16, acc);
#pragma unroll
      for (int ct = 0; ct < 4; ++ct)
#pragma unroll
        for (int i = 0; i < 4; ++i) {
          int row = row0 + rowbase + quad * 4 + i;
          int col = 128 + colbase + ct * 16 + l16;
          kv[(size_t)row * 256 + col] = f2bf(acc[ct][i]);
        }
    }

    // -------- fenced grid barrier: all blocks' kv visible ------------------
    grid_barrier(barrier_cnt, (unsigned)(NBLK * (l + 1)));
    commit_stage(pre, Bs, t);              // Wo (Bs free: mfma v pre-barrier)
    issue_stage(wl + WSEG_QKV + WSEG_O, 128, pre, t);   // -> W1 c0

    // ---------------- attention (48 rows x 8 heads, one per thread) --------
    {
      const int rL = t >> 3, h = t & 7;
      const int s = row0 + rL - bS;
      const int cnt = sCnt[rL];
      float q[16];
      {
        u16x8 qa = *(const u16x8*)&Cs[rL * 128 + (((2 * h) ^ (rL & 15)) << 3)];
        u16x8 qb = *(const u16x8*)&Cs[rL * 128 + (((2 * h + 1) ^ (rL & 15)) << 3)];
#pragma unroll
        for (int j = 0; j < 8; ++j) { q[j] = bf2f(qa[j]); q[8 + j] = bf2f(qb[j]); }
      }
      float m = -1e30f, lsum = 0.f;
      float o16[16];
#pragma unroll
      for (int j = 0; j < 16; ++j) o16[j] = 0.f;
      for (int jb = 0; jb < cnt; jb += 8) {
        u16x8 K[8][2], V[8][2];
#pragma unroll
        for (int u = 0; u < 8; ++u) {
          int j = jb + u;
          int key = 0;
          if (j < cnt) key = (j < LKEY) ? sKeys[rL * LKEY + j] : adj[s * MAXDEG + j];
          const unsigned short* kp = kv + (size_t)(bS + key) * 256 + h * 16;
          K[u][0] = *(const u16x8*)(kp);
          K[u][1] = *(const u16x8*)(kp + 8);
          V[u][0] = *(const u16x8*)(kp + 128);
          V[u][1] = *(const u16x8*)(kp + 136);
        }
#pragma unroll
        for (int u = 0; u < 8; ++u) {
          float dot = 0.f;
#pragma unroll
          for (int j = 0; j < 8; ++j) {
            dot = fmaf(q[j], bf2f(K[u][0][j]), dot);
            dot = fmaf(q[8 + j], bf2f(K[u][1][j]), dot);
          }
          dot *= 0.25f;
          if (jb + u >= cnt) dot = -1e30f;
          const float mn = fmaxf(m, dot);
          const float rescale = __expf(m - mn);
          const float e = __expf(dot - mn);
          lsum = lsum * rescale + e;
#pragma unroll
          for (int j = 0; j < 8; ++j) {
            o16[j]     = o16[j]     * rescale + e * bf2f(V[u][0][j]);
            o16[8 + j] = o16[8 + j] * rescale + e * bf2f(V[u][1][j]);
          }
          m = mn;
        }
      }
      const float inv = 1.f / lsum;
      u16x8 pk0, pk1;
#pragma unroll
      for (int j = 0; j < 8; ++j) {
        pk0[j] = f2bf(o16[j] * inv);
        pk1[j] = f2bf(o16[8 + j] * inv);
      }
      *(u16x8*)&As[rL * 128 + (((2 * h) ^ (rL & 15)) << 3)] = pk0;
      *(u16x8*)&As[rL * 128 + (((2 * h + 1) ^ (rL & 15)) << 3)] = pk1;
    }
    __syncthreads();                       // As(o) + Bs(Wo) ready

    // ---------------- x' = x + o@Wo; LN2*te; FFN; residual -----------------
    f32x4 acc1[4];
#pragma unroll
    for (int j = 0; j < 4; ++j) acc1[j] = f32x4{0.f, 0.f, 0.f, 0.f};
    mfma4(As, Bs, rowbase, colbase, quad, l16, acc1);
    f32x4 xp[4];
#pragma unroll
    for (int ct = 0; ct < 4; ++ct)
#pragma unroll
      for (int i = 0; i < 4; ++i) xp[ct][i] = xreg[ct][i] + acc1[ct][i];
#pragma unroll
    for (int i = 0; i < 4; ++i) {
      float s = xp[0][i] + xp[1][i] + xp[2][i] + xp[3][i];
      for (int off = 1; off < 16; off <<= 1) s += __shfl_xor(s, off);
      if (l16 == 0) red1[wc][rowbase + quad * 4 + i] = s;
    }
    __syncthreads();
    float mu_[4], rs_[4];
#pragma unroll
    for (int i = 0; i < 4; ++i) {
      int r = rowbase + quad * 4 + i;
      mu_[i] = (red1[0][r] + red1[1][r]) * (1.f / 128.f);
      float sq = 0.f;
#pragma unroll
      for (int ct = 0; ct < 4; ++ct) { float d = xp[ct][i] - mu_[i]; sq += d * d; }
      for (int off = 1; off < 16; off <<= 1) sq += __shfl_xor(sq, off);
      if (l16 == 0) red2[wc][r] = sq;
    }
    __syncthreads();
#pragma unroll
    for (int i = 0; i < 4; ++i) {
      int r = rowbase + quad * 4 + i;
      rs_[i] = rsqrtf((red2[0][r] + red2[1][r]) * (1.f / 128.f) + 1e-5f);
    }
#pragma unroll
    for (int ct = 0; ct < 4; ++ct)
#pragma unroll
      for (int i = 0; i < 4; ++i) {
        int rowL = rowbase + quad * 4 + i;
        int col = colbase + ct * 16 + l16;
        float h2 = (xp[ct][i] - mu_[i]) * rs_[i] * g2l[col] + b2l[col];
        h2 *= table[tbase + col];
        As[rowL * 128 + (((col >> 3) ^ (rowL & 15)) << 3) + (col & 7)] = f2bf(h2);
      }
    f32x4 acc2[4];
#pragma unroll
    for (int j = 0; j < 4; ++j) acc2[j] = f32x4{0.f, 0.f, 0.f, 0.f};
    const unsigned short* w1 = wl + WSEG_QKV + WSEG_O;
    const unsigned short* w2 = wl + WSEG_QKV + WSEG_O + WSEG_1;
    for (int c = 0; c < 4; ++c) {
      __syncthreads();                     // As(h2)/Cs ready; Bs reads done
      commit_stage(pre, Bs, t);            // W1 chunk c
      __syncthreads();
      issue_stage(w2 + (size_t)c * 128, 512, pre, t);   // -> W2 chunk c
      f32x4 accF[4];
#pragma unroll
      for (int j = 0; j < 4; ++j) accF[j] = f32x4{0.f, 0.f, 0.f, 0.f};
      mfma4(As, Bs, rowbase, colbase, quad, l16, accF);
#pragma unroll
      for (int ct = 0; ct < 4; ++ct)
#pragma unroll
        for (int i = 0; i < 4; ++i) {
          int rowL = rowbase + quad * 4 + i;
          int col = colbase + ct * 16 + l16;
          Cs[rowL * 128 + (((col >> 3) ^ (rowL & 15)) << 3) + (col & 7)] =
              f2bf(fmaxf(accF[ct][i], 0.f));
        }
      __syncthreads();                     // Cs(hf) ready; Bs(W1c) reads done
      commit_stage(pre, Bs, t);            // W2 chunk c
      __syncthreads();
      if (c < 3) issue_stage(w1 + (size_t)(c + 1) * 128 * 128, 128, pre, t);
      else if (l < L_ - 1) issue_stage(wbf + (size_t)(l + 1) * WLAYER, 128, pre, t);
      mfma4(Cs, Bs, rowbase, colbase, quad, l16, acc2);
    }
    // epilogue
    if (l < L_ - 1) {
#pragma unroll
      for (int ct = 0; ct < 4; ++ct)
#pragma unroll
        for (int i = 0; i < 4; ++i) xreg[ct][i] = xp[ct][i] + acc2[ct][i];
    } else {
      float pr[4] = {0.f, 0.f, 0.f, 0.f};
#pragma unroll
      for (int ct = 0; ct < 4; ++ct)
#pragma unroll
        for (int i = 0; i < 4; ++i)
          pr[i] += (xp[ct][i] + acc2[ct][i]) * fcw[colbase + ct * 16 + l16];
#pragma unroll
      for (int i = 0; i < 4; ++i) {
        float s = pr[i];
        for (int off = 1; off < 16; off <<= 1) s += __shfl_xor(s, off);
        if (l16 == 0) red1[wc][rowbase + quad * 4 + i] = s;
      }
      __syncthreads();
      if (wc == 0 && l16 == 0)
#pragma unroll
        for (int i = 0; i < 4; ++i) {
          int r = rowbase + quad * 4 + i;
          out[row0 + r] = red1[0][r] + red1[1][r] + fcb[0];
        }
    }
  }
}

// ---------------------------------------------------------------------------
extern "C" void kernel_launch(void* const* d_in, const int* in_sizes, int n_in,
                              void* d_out, int out_size, void* d_ws, size_t ws_size,
                              hipStream_t stream) {
  const float* r_t       = (const float*)d_in[0];
  const int*   t         = (const int*)d_in[1];
  const int*   pcm       = (const int*)d_in[2];
  const float* src_embed = (const float*)d_in[4];
  const float* time_tab  = (const float*)d_in[5];
  const float* Wq = (const float*)d_in[6];
  const float* Wk = (const float*)d_in[7];
  const float* Wv = (const float*)d_in[8];
  const float* Wo = (const float*)d_in[9];
  const float* W1 = (const float*)d_in[10];
  const float* W2 = (const float*)d_in[11];
  const float* g1 = (const float*)d_in[12];
  const float* b1 = (const float*)d_in[13];
  const float* g2 = (const float*)d_in[14];
  const float* b2 = (const float*)d_in[15];
  const float* fc_w = (const float*)d_in[16];
  const float* fc_b = (const float*)d_in[17];
  float* out = (float*)d_out;

  char* ws = (char*)d_ws;
  size_t off = 0;
  auto alloc = [&](size_t bytes) -> void* {
    void* p = ws + off;
    off = (off + bytes + 255) & ~(size_t)255;
    return p;
  };
  float*          x    = (float*)alloc((size_t)ROWS * D_ * 4);
  unsigned short* kv0  = (unsigned short*)alloc((size_t)ROWS * 256 * 2);
  unsigned short* kv1  = (unsigned short*)alloc((size_t)ROWS * 256 * 2);
  int*            adj  = (int*)alloc((size_t)S_ * MAXDEG * 4);
  int*            adjc = (int*)alloc((size_t)S_ * 4);
  unsigned short* wbf  = (unsigned short*)alloc((size_t)L_ * WLAYER * 2);
  unsigned*       bcnt = (unsigned*)alloc(256);

  adj_kernel<<<S_, 64, 0, stream>>>(pcm, adj, adjc);
  wconv_kernel<<<(L_ * WLAYER + 255) / 256, 256, 0, stream>>>(Wq, Wk, Wv, Wo, W1, W2, wbf);
  xinit_kernel<<<ROWS, 128, 0, stream>>>(r_t, adj, adjc, src_embed, t, time_tab, x, bcnt);

  mega_kernel<<<NBLK, 384, 0, stream>>>(x, kv0, kv1, wbf, g1, b1, g2, b2,
                                        t, time_tab, adj, adjc, fc_w, fc_b, out, bcnt);
}

// Round 10
// 360.156 us; speedup vs baseline: 1.6416x; 1.6416x over previous
//
#include <hip/hip_runtime.h>
#include <cmath>
#include <cstdint>

// Problem constants (from reference)
constexpr int B_ = 8, N_ = 1024, M_ = 512, D_ = 128, S_ = 1536, L_ = 6, DFF_ = 512;
constexpr int ROWS = B_ * S_;    // 12288
constexpr int MAXDEG = 64;       // max attention row degree (actual ~4-20)
constexpr int LKEY = 32;         // LDS-cached keys per row
constexpr int RPB  = 48;         // rows per block
constexpr int NBLK = ROWS / RPB; // 256 persistent blocks (all hardware-resident)

typedef __bf16 bf16x8 __attribute__((ext_vector_type(8)));
typedef float  f32x4  __attribute__((ext_vector_type(4)));
typedef unsigned short u16x8 __attribute__((ext_vector_type(8)));

__device__ inline unsigned short f2bf(float f) {  // RNE fp32 -> bf16
  unsigned u = __float_as_uint(f);
  u += 0x7fffu + ((u >> 16) & 1u);
  return (unsigned short)(u >> 16);
}
__device__ inline float bf2f(unsigned short u) {
  return __uint_as_float(((unsigned)u) << 16);
}
__device__ inline void ull2f4(unsigned long long u, float* f) {  // 4 bf16 -> fp32
  f[0] = bf2f((unsigned short)(u));
  f[1] = bf2f((unsigned short)(u >> 16));
  f[2] = bf2f((unsigned short)(u >> 32));
  f[3] = bf2f((unsigned short)(u >> 48));
}

// ---------------------------------------------------------------------------
// Adjacency from pcm (one wave per row). exp(-1e9-max) underflows to 0 in
// fp32 => sparse attention over this list == dense masked softmax.
// ---------------------------------------------------------------------------
__global__ void adj_kernel(const int* __restrict__ pcm, int* __restrict__ adj,
                           int* __restrict__ adjcnt) {
  int s = blockIdx.x;
  int lane = threadIdx.x;
  int count = 0;
  for (int base = 0; base < S_; base += 64) {
    int k = base + lane;
    bool allowed;
    if (k == s) allowed = true;
    else if (s < N_ && k >= N_) allowed = pcm[(k - N_) * N_ + s] != 0;
    else if (s >= N_ && k < N_) allowed = pcm[(s - N_) * N_ + k] != 0;
    else allowed = false;
    unsigned long long bal = __ballot(allowed);
    if (allowed) {
      int slot = count + __popcll(bal & ((1ull << lane) - 1ull));
      if (slot < MAXDEG) adj[s * MAXDEG + slot] = k;
    }
    count += __popcll(bal);
  }
  if (lane == 0) adjcnt[s] = count < MAXDEG ? count : MAXDEG;
}

// ---------------------------------------------------------------------------
// x init; also zeroes the grid-barrier counter (ws poisoned 0xAA per call).
// ---------------------------------------------------------------------------
__global__ void xinit_kernel(const float* __restrict__ r_t, const int* __restrict__ adj,
                             const int* __restrict__ adjcnt, const float* __restrict__ se,
                             const int* __restrict__ tt, const float* __restrict__ table,
                             float* __restrict__ x, unsigned* __restrict__ barrier_cnt) {
  int bs = blockIdx.x;
  int b = bs / S_, s = bs % S_;
  int d = threadIdx.x;
  if (bs == 0 && d == 0)
    __hip_atomic_store(barrier_cnt, 0u, __ATOMIC_RELAXED, __HIP_MEMORY_SCOPE_AGENT);
  float node;
  if (s < N_) {
    node = fabsf(r_t[b * N_ + s]);
  } else {
    int cnt = adjcnt[s];
    float sum = 0.f;
    for (int j = 0; j < cnt; ++j) {
      int k = adj[s * MAXDEG + j];
      if (k < N_) {
        float r = r_t[b * N_ + k];
        sum += (r < 0.f) ? 1.f : (r > 0.f ? 0.f : 0.5f);
      }
    }
    node = fmodf(sum, 2.0f);
  }
  x[(size_t)bs * D_ + d] = table[tt[b] * D_ + d] * se[s * D_ + d] * node;
}

// ---------------------------------------------------------------------------
// Weight convert: fp32 [K][N] -> bf16 transposed [N][K], per layer packed as
//   [3*128][128] (q,k,v) | [128][128] (o) | [512][128] (w1) | [128][512] (w2)
// ---------------------------------------------------------------------------
constexpr int WSEG_QKV = 3 * D_ * D_;
constexpr int WSEG_O   = D_ * D_;
constexpr int WSEG_1   = D_ * DFF_;
constexpr int WSEG_2   = DFF_ * D_;
constexpr int WLAYER   = WSEG_QKV + WSEG_O + WSEG_1 + WSEG_2;  // 196608

__global__ void wconv_kernel(const float* __restrict__ Wq, const float* __restrict__ Wk,
                             const float* __restrict__ Wv, const float* __restrict__ Wo,
                             const float* __restrict__ W1, const float* __restrict__ W2,
                             unsigned short* __restrict__ out) {
  int idx = blockIdx.x * blockDim.x + threadIdx.x;
  if (idx >= L_ * WLAYER) return;
  int l = idx / WLAYER, r = idx % WLAYER;
  float v;
  if (r < WSEG_QKV) {
    int which = r / (D_ * D_), i = r % (D_ * D_);
    int n = i / D_, kk = i % D_;
    const float* W = which == 0 ? Wq : (which == 1 ? Wk : Wv);
    v = W[(size_t)l * D_ * D_ + kk * D_ + n];
  } else if (r < WSEG_QKV + WSEG_O) {
    int i = r - WSEG_QKV;
    int n = i / D_, kk = i % D_;
    v = Wo[(size_t)l * D_ * D_ + kk * D_ + n];
  } else if (r < WSEG_QKV + WSEG_O + WSEG_1) {
    int i = r - WSEG_QKV - WSEG_O;
    int n = i / D_, kk = i % D_;
    v = W1[(size_t)l * D_ * DFF_ + kk * DFF_ + n];
  } else {
    int i = r - WSEG_QKV - WSEG_O - WSEG_1;
    int n = i / DFF_, kk = i % DFF_;
    v = W2[(size_t)l * DFF_ * D_ + kk * D_ + n];
  }
  out[idx] = f2bf(v);
}

// ---------------------------------------------------------------------------
// MFMA helper: wave tile = 16 rows x 64 cols (4 tiles of 16x16), K=128 in 4
// steps of 32. LDS: 16B chunks XOR-swizzled [row*128 + ((c^(row&15))<<3)].
// ---------------------------------------------------------------------------
__device__ __forceinline__ void mfma4(const unsigned short* As, const unsigned short* Bs,
                                      int rowbase, int colbase, int quad, int l16,
                                      f32x4 (&acc)[4]) {
#pragma unroll
  for (int kk = 0; kk < 4; ++kk) {
    int cb = kk * 4 + quad;
    int row = rowbase + l16;
    bf16x8 a = __builtin_bit_cast(bf16x8, *(const uint4*)&As[row * 128 + ((cb ^ (row & 15)) << 3)]);
    bf16x8 bb[4];
#pragma unroll
    for (int ct = 0; ct < 4; ++ct) {
      int n = colbase + ct * 16 + l16;
      bb[ct] = __builtin_bit_cast(bf16x8, *(const uint4*)&Bs[n * 128 + ((cb ^ (n & 15)) << 3)]);
    }
#pragma unroll
    for (int ct = 0; ct < 4; ++ct)
      acc[ct] = __builtin_amdgcn_mfma_f32_16x16x32_bf16(a, bb[ct], acc[ct], 0, 0, 0);
  }
}

// ---------------------------------------------------------------------------
// Fence-free grid barrier. Correctness: kv is the ONLY cross-block data and
// all kv traffic uses agent-scope atomics (coherent at the device point,
// bypassing the non-coherent per-XCD L2s). __syncthreads drains each wave's
// stores (compiler emits s_waitcnt vmcnt(0) before s_barrier), so when the
// last block increments the counter, all kv stores are visible. No
// __threadfence => no buffer_wbl2/inv => weights stay L2-warm across layers.
// ---------------------------------------------------------------------------
__device__ __forceinline__ void grid_barrier(unsigned* cnt, unsigned target) {
  __syncthreads();
  if (threadIdx.x == 0) {
    __hip_atomic_fetch_add(cnt, 1u, __ATOMIC_RELAXED, __HIP_MEMORY_SCOPE_AGENT);
    while (__hip_atomic_load(cnt, __ATOMIC_RELAXED, __HIP_MEMORY_SCOPE_AGENT) < target)
      __builtin_amdgcn_s_sleep(4);
  }
  __syncthreads();
}

// ---------------------------------------------------------------------------
// Persistent mega-kernel: all 6 layers + fc head.
// grid = 256 blocks x 384 thr (6 waves); block owns 48 rows.
// x in registers; Q block-local (Cs, swizzled); bf16 K/V cross blocks via
// agent-scope atomics (dbuffered); one fence-free barrier per layer.
// LDS: As 12K + Bs 32K + Cs 12K + sKeys 6K + red 0.8K ~= 63 KB.
// ---------------------------------------------------------------------------
__global__ void __launch_bounds__(384) mega_kernel(
    const float* __restrict__ x0, unsigned short* __restrict__ kv0,
    unsigned short* __restrict__ kv1, const unsigned short* __restrict__ wbf,
    const float* __restrict__ g1, const float* __restrict__ b1,
    const float* __restrict__ g2, const float* __restrict__ b2,
    const int* __restrict__ tt, const float* __restrict__ table,
    const int* __restrict__ adj, const int* __restrict__ adjc,
    const float* __restrict__ fcw, const float* __restrict__ fcb,
    float* __restrict__ out, unsigned* barrier_cnt) {
  __shared__ unsigned short As[RPB * 128];
  __shared__ unsigned short Bs[128 * 128];
  __shared__ unsigned short Cs[RPB * 128];
  __shared__ float red1[2][RPB], red2[2][RPB];
  __shared__ int sKeys[RPB * LKEY];
  __shared__ int sCnt[RPB];
  const int row0 = blockIdx.x * RPB;
  const int b = row0 / S_;
  const int bS = b * S_;
  const int t = threadIdx.x, w = t >> 6, lane = t & 63, quad = lane >> 4, l16 = lane & 15;
  const int wr = w >> 1, wc = w & 1;
  const int rowbase = wr * 16, colbase = wc * 64;
  const int tbase = tt[b] * D_;

  // persistent x in registers (MFMA C-layout)
  f32x4 xreg[4];
#pragma unroll
  for (int ct = 0; ct < 4; ++ct)
#pragma unroll
    for (int i = 0; i < 4; ++i) {
      int row = row0 + rowbase + quad * 4 + i;
      int col = colbase + ct * 16 + l16;
      xreg[ct][i] = x0[(size_t)row * D_ + col];
    }
  // cache block's adjacency in LDS
  if (t < RPB) sCnt[t] = adjc[row0 + t - bS];
  for (int i = t; i < RPB * LKEY; i += 384) {
    int r = i / LKEY, j = i % LKEY;
    sKeys[i] = adj[(row0 + r - bS) * MAXDEG + j];  // tail values unused (clamped)
  }

  for (int l = 0; l < L_; ++l) {
    const unsigned short* wl = wbf + (size_t)l * WLAYER;
    const float* g1l = g1 + l * D_;
    const float* b1l = b1 + l * D_;
    const float* g2l = g2 + l * D_;
    const float* b2l = b2 + l * D_;
    unsigned short* kv = (l & 1) ? kv1 : kv0;

    // ---------------- LN1 on register x -> bf16 h in As --------------------
    float mu1[4], rs1[4];
#pragma unroll
    for (int i = 0; i < 4; ++i) {
      float s = xreg[0][i] + xreg[1][i] + xreg[2][i] + xreg[3][i];
      for (int off = 1; off < 16; off <<= 1) s += __shfl_xor(s, off);
      if (l16 == 0) red1[wc][rowbase + quad * 4 + i] = s;
    }
    __syncthreads();
#pragma unroll
    for (int i = 0; i < 4; ++i) {
      int r = rowbase + quad * 4 + i;
      mu1[i] = (red1[0][r] + red1[1][r]) * (1.f / 128.f);
      float sq = 0.f;
#pragma unroll
      for (int ct = 0; ct < 4; ++ct) { float d = xreg[ct][i] - mu1[i]; sq += d * d; }
      for (int off = 1; off < 16; off <<= 1) sq += __shfl_xor(sq, off);
      if (l16 == 0) red2[wc][r] = sq;
    }
    __syncthreads();
#pragma unroll
    for (int i = 0; i < 4; ++i) {
      int r = rowbase + quad * 4 + i;
      rs1[i] = rsqrtf((red2[0][r] + red2[1][r]) * (1.f / 128.f) + 1e-5f);
    }
#pragma unroll
    for (int ct = 0; ct < 4; ++ct)
#pragma unroll
      for (int i = 0; i < 4; ++i) {
        int rowL = rowbase + quad * 4 + i;
        int col = colbase + ct * 16 + l16;
        float h = (xreg[ct][i] - mu1[i]) * rs1[i] * g1l[col] + b1l[col];
        As[rowL * 128 + (((col >> 3) ^ (rowL & 15)) << 3) + (col & 7)] = f2bf(h);
      }

    // ------- QKV GEMMs: K then V (via Cs -> atomic kv), then Q -> Cs -------
    const int segs[3] = {1, 2, 0};  // weight rows: q=0,k=1,v=2
    for (int si = 0; si < 3; ++si) {
      const int seg = segs[si];
      for (int i = t; i < 2048; i += 384) {  // Bs <- seg's 128x128 tile
        int rr = i >> 4, cc = i & 15;
        uint4 vb = *(const uint4*)&wl[(size_t)(seg * 128 + rr) * 128 + cc * 8];
        *(uint4*)&Bs[rr * 128 + ((cc ^ (rr & 15)) << 3)] = vb;
      }
      __syncthreads();  // Bs staged; also covers As/Cs hazards
      f32x4 acc[4];
#pragma unroll
      for (int j = 0; j < 4; ++j) acc[j] = f32x4{0.f, 0.f, 0.f, 0.f};
      mfma4(As, Bs, rowbase, colbase, quad, l16, acc);
      if (seg == 0) {  // Q -> Cs (swizzled A-layout, stays for attention)
#pragma unroll
        for (int ct = 0; ct < 4; ++ct)
#pragma unroll
          for (int i = 0; i < 4; ++i) {
            int rowL = rowbase + quad * 4 + i;
            int col = colbase + ct * 16 + l16;
            Cs[rowL * 128 + (((col >> 3) ^ (rowL & 15)) << 3) + (col & 7)] = f2bf(acc[ct][i]);
          }
      } else {  // K or V -> Cs (linear) -> coalesced agent-scope dword stores
#pragma unroll
        for (int ct = 0; ct < 4; ++ct)
#pragma unroll
          for (int i = 0; i < 4; ++i) {
            int rowL = rowbase + quad * 4 + i;
            int col = colbase + ct * 16 + l16;
            Cs[rowL * 128 + col] = f2bf(acc[ct][i]);
          }
        __syncthreads();
        const int cbase = (seg == 1) ? 0 : 128;
        for (int i = t; i < RPB * 64; i += 384) {  // 64 dwords per row
          int rL = i >> 6, cw = i & 63;
          unsigned u = *(const unsigned*)&Cs[rL * 128 + cw * 2];
          __hip_atomic_store((unsigned*)&kv[(size_t)(row0 + rL) * 256 + cbase + cw * 2],
                             u, __ATOMIC_RELAXED, __HIP_MEMORY_SCOPE_AGENT);
        }
      }
      __syncthreads();  // before next seg overwrites Bs/Cs
    }

    // -------- fence-free grid barrier: all blocks' kv visible --------------
    grid_barrier(barrier_cnt, (unsigned)(NBLK * (l + 1)));

    // stage Bs <- Wo^T (L2-warm now; loads fly under the attention gather)
    for (int i = t; i < 2048; i += 384) {
      int rr = i >> 4, cc = i & 15;
      uint4 vb = *(const uint4*)&wl[(size_t)(WSEG_QKV + rr * 128 + cc * 8)];
      *(uint4*)&Bs[rr * 128 + ((cc ^ (rr & 15)) << 3)] = vb;
    }

    // ---------------- attention (48 rows x 8 heads, one per thread) --------
    {
      const int rL = t >> 3, h = t & 7;
      const int s = row0 + rL - bS;
      const int cnt = sCnt[rL];
      float q[16];
      {
        u16x8 qa = *(const u16x8*)&Cs[rL * 128 + (((2 * h) ^ (rL & 15)) << 3)];
        u16x8 qb = *(const u16x8*)&Cs[rL * 128 + (((2 * h + 1) ^ (rL & 15)) << 3)];
#pragma unroll
        for (int j = 0; j < 8; ++j) { q[j] = bf2f(qa[j]); q[8 + j] = bf2f(qb[j]); }
      }
      float m = -1e30f, lsum = 0.f;
      float o16[16];
#pragma unroll
      for (int j = 0; j < 16; ++j) o16[j] = 0.f;
      for (int jb = 0; jb < cnt; jb += 4) {  // 4 neighbors in flight
        unsigned long long K[4][4], V[4][4];
#pragma unroll
        for (int u = 0; u < 4; ++u) {
          int j = jb + u;
          int key = 0;
          if (j < cnt) key = (j < LKEY) ? sKeys[rL * LKEY + j] : adj[s * MAXDEG + j];
          const unsigned long long* kp =
              (const unsigned long long*)(kv + (size_t)(bS + key) * 256 + h * 16);
#pragma unroll
          for (int c = 0; c < 4; ++c) {
            K[u][c] = __hip_atomic_load(kp + c, __ATOMIC_RELAXED, __HIP_MEMORY_SCOPE_AGENT);
            V[u][c] = __hip_atomic_load(kp + 32 + c, __ATOMIC_RELAXED, __HIP_MEMORY_SCOPE_AGENT);
          }
        }
#pragma unroll
        for (int u = 0; u < 4; ++u) {
          float kf[16], vf[16];
#pragma unroll
          for (int c = 0; c < 4; ++c) { ull2f4(K[u][c], kf + 4 * c); ull2f4(V[u][c], vf + 4 * c); }
          float dot = 0.f;
#pragma unroll
          for (int j = 0; j < 16; ++j) dot = fmaf(q[j], kf[j], dot);
          dot *= 0.25f;  // 1/sqrt(HD)
          if (jb + u >= cnt) dot = -1e30f;  // masked pad -> e = 0
          const float mn = fmaxf(m, dot);
          const float rescale = __expf(m - mn);
          const float e = __expf(dot - mn);
          lsum = lsum * rescale + e;
#pragma unroll
          for (int j = 0; j < 16; ++j) o16[j] = o16[j] * rescale + e * vf[j];
          m = mn;
        }
      }
      const float inv = 1.f / lsum;
      u16x8 pk0, pk1;
#pragma unroll
      for (int j = 0; j < 8; ++j) {
        pk0[j] = f2bf(o16[j] * inv);
        pk1[j] = f2bf(o16[8 + j] * inv);
      }
      *(u16x8*)&As[rL * 128 + (((2 * h) ^ (rL & 15)) << 3)] = pk0;
      *(u16x8*)&As[rL * 128 + (((2 * h + 1) ^ (rL & 15)) << 3)] = pk1;
    }
    __syncthreads();  // As(o) writes + Bs(Wo) staging complete

    // ---------------- x' = x + o@Wo; LN2*te; FFN; residual -----------------
    f32x4 acc1[4];
#pragma unroll
    for (int j = 0; j < 4; ++j) acc1[j] = f32x4{0.f, 0.f, 0.f, 0.f};
    mfma4(As, Bs, rowbase, colbase, quad, l16, acc1);
    f32x4 xp[4];
#pragma unroll
    for (int ct = 0; ct < 4; ++ct)
#pragma unroll
      for (int i = 0; i < 4; ++i) xp[ct][i] = xreg[ct][i] + acc1[ct][i];
#pragma unroll
    for (int i = 0; i < 4; ++i) {
      float s = xp[0][i] + xp[1][i] + xp[2][i] + xp[3][i];
      for (int off = 1; off < 16; off <<= 1) s += __shfl_xor(s, off);
      if (l16 == 0) red1[wc][rowbase + quad * 4 + i] = s;
    }
    __syncthreads();
    float mu_[4], rs_[4];
#pragma unroll
    for (int i = 0; i < 4; ++i) {
      int r = rowbase + quad * 4 + i;
      mu_[i] = (red1[0][r] + red1[1][r]) * (1.f / 128.f);
      float sq = 0.f;
#pragma unroll
      for (int ct = 0; ct < 4; ++ct) { float d = xp[ct][i] - mu_[i]; sq += d * d; }
      for (int off = 1; off < 16; off <<= 1) sq += __shfl_xor(sq, off);
      if (l16 == 0) red2[wc][r] = sq;
    }
    __syncthreads();
#pragma unroll
    for (int i = 0; i < 4; ++i) {
      int r = rowbase + quad * 4 + i;
      rs_[i] = rsqrtf((red2[0][r] + red2[1][r]) * (1.f / 128.f) + 1e-5f);
    }
#pragma unroll
    for (int ct = 0; ct < 4; ++ct)
#pragma unroll
      for (int i = 0; i < 4; ++i) {
        int rowL = rowbase + quad * 4 + i;
        int col = colbase + ct * 16 + l16;
        float h2 = (xp[ct][i] - mu_[i]) * rs_[i] * g2l[col] + b2l[col];
        h2 *= table[tbase + col];
        As[rowL * 128 + (((col >> 3) ^ (rowL & 15)) << 3) + (col & 7)] = f2bf(h2);
      }
    f32x4 acc2[4];
#pragma unroll
    for (int j = 0; j < 4; ++j) acc2[j] = f32x4{0.f, 0.f, 0.f, 0.f};
    const unsigned short* w1 = wl + WSEG_QKV + WSEG_O;
    const unsigned short* w2 = wl + WSEG_QKV + WSEG_O + WSEG_1;
    for (int c = 0; c < 4; ++c) {
      for (int i = t; i < 2048; i += 384) {
        int rr = i >> 4, cc = i & 15;
        uint4 vb = *(const uint4*)&w1[(size_t)(c * 128 + rr) * 128 + cc * 8];
        *(uint4*)&Bs[rr * 128 + ((cc ^ (rr & 15)) << 3)] = vb;
      }
      __syncthreads();
      f32x4 accF[4];
#pragma unroll
      for (int j = 0; j < 4; ++j) accF[j] = f32x4{0.f, 0.f, 0.f, 0.f};
      mfma4(As, Bs, rowbase, colbase, quad, l16, accF);
#pragma unroll
      for (int ct = 0; ct < 4; ++ct)
#pragma unroll
        for (int i = 0; i < 4; ++i) {
          int rowL = rowbase + quad * 4 + i;
          int col = colbase + ct * 16 + l16;
          Cs[rowL * 128 + (((col >> 3) ^ (rowL & 15)) << 3) + (col & 7)] =
              f2bf(fmaxf(accF[ct][i], 0.f));
        }
      __syncthreads();  // Bs(W1) reads + Cs writes drained
      for (int i = t; i < 2048; i += 384) {
        int rr = i >> 4, cc = i & 15;
        uint4 vb = *(const uint4*)&w2[(size_t)rr * 512 + c * 128 + cc * 8];
        *(uint4*)&Bs[rr * 128 + ((cc ^ (rr & 15)) << 3)] = vb;
      }
      __syncthreads();
      mfma4(Cs, Bs, rowbase, colbase, quad, l16, acc2);
      __syncthreads();  // before next c overwrites Bs
    }
    // epilogue: x'' = x' + ffn (registers only)
    if (l < L_ - 1) {
#pragma unroll
      for (int ct = 0; ct < 4; ++ct)
#pragma unroll
        for (int i = 0; i < 4; ++i) xreg[ct][i] = xp[ct][i] + acc2[ct][i];
    } else {
      float pr[4] = {0.f, 0.f, 0.f, 0.f};
#pragma unroll
      for (int ct = 0; ct < 4; ++ct)
#pragma unroll
        for (int i = 0; i < 4; ++i)
          pr[i] += (xp[ct][i] + acc2[ct][i]) * fcw[colbase + ct * 16 + l16];
#pragma unroll
      for (int i = 0; i < 4; ++i) {
        float s = pr[i];
        for (int off = 1; off < 16; off <<= 1) s += __shfl_xor(s, off);
        if (l16 == 0) red1[wc][rowbase + quad * 4 + i] = s;
      }
      __syncthreads();
      if (wc == 0 && l16 == 0)
#pragma unroll
        for (int i = 0; i < 4; ++i) {
          int r = rowbase + quad * 4 + i;
          out[row0 + r] = red1[0][r] + red1[1][r] + fcb[0];
        }
    }
  }
}

// ---------------------------------------------------------------------------
extern "C" void kernel_launch(void* const* d_in, const int* in_sizes, int n_in,
                              void* d_out, int out_size, void* d_ws, size_t ws_size,
                              hipStream_t stream) {
  const float* r_t       = (const float*)d_in[0];
  const int*   t         = (const int*)d_in[1];
  const int*   pcm       = (const int*)d_in[2];
  const float* src_embed = (const float*)d_in[4];
  const float* time_tab  = (const float*)d_in[5];
  const float* Wq = (const float*)d_in[6];
  const float* Wk = (const float*)d_in[7];
  const float* Wv = (const float*)d_in[8];
  const float* Wo = (const float*)d_in[9];
  const float* W1 = (const float*)d_in[10];
  const float* W2 = (const float*)d_in[11];
  const float* g1 = (const float*)d_in[12];
  const float* b1 = (const float*)d_in[13];
  const float* g2 = (const float*)d_in[14];
  const float* b2 = (const float*)d_in[15];
  const float* fc_w = (const float*)d_in[16];
  const float* fc_b = (const float*)d_in[17];
  float* out = (float*)d_out;

  char* ws = (char*)d_ws;
  size_t off = 0;
  auto alloc = [&](size_t bytes) -> void* {
    void* p = ws + off;
    off = (off + bytes + 255) & ~(size_t)255;
    return p;
  };
  float*          x    = (float*)alloc((size_t)ROWS * D_ * 4);
  unsigned short* kv0  = (unsigned short*)alloc((size_t)ROWS * 256 * 2);
  unsigned short* kv1  = (unsigned short*)alloc((size_t)ROWS * 256 * 2);
  int*            adj  = (int*)alloc((size_t)S_ * MAXDEG * 4);
  int*            adjc = (int*)alloc((size_t)S_ * 4);
  unsigned short* wbf  = (unsigned short*)alloc((size_t)L_ * WLAYER * 2);
  unsigned*       bcnt = (unsigned*)alloc(256);

  adj_kernel<<<S_, 64, 0, stream>>>(pcm, adj, adjc);
  wconv_kernel<<<(L_ * WLAYER + 255) / 256, 256, 0, stream>>>(Wq, Wk, Wv, Wo, W1, W2, wbf);
  xinit_kernel<<<ROWS, 128, 0, stream>>>(r_t, adj, adjc, src_embed, t, time_tab, x, bcnt);

  mega_kernel<<<NBLK, 384, 0, stream>>>(x, kv0, kv1, wbf, g1, b1, g2, b2,
                                        t, time_tab, adj, adjc, fc_w, fc_b, out, bcnt);
}